// Round 1
// baseline (427.245 us; speedup 1.0000x reference)
//
#include <hip/hip_runtime.h>

#define DIM 128

// One half-wave (32 lanes) per row of 128 floats; each lane owns a float4
// column slice (16 B/lane loads/stores — coalescing sweet spot).
__global__ __launch_bounds__(256) void qop_kernel(
    const float* __restrict__ sr, const float* __restrict__ si,
    const float* __restrict__ p,
    float* __restrict__ out_r, float* __restrict__ out_i, int M)
{
    const int lane32 = threadIdx.x & 31;      // float4 index within the row
    const int rowInBlock = threadIdx.x >> 5;  // 0..7
    const int rowsPerBlock = blockDim.x >> 5; // 8

    // Per-lane column parameters (fixed across all rows this lane touches).
    const float4 p4 = reinterpret_cast<const float4*>(p)[lane32];
    float4 d4;
    d4.x = 1.0f / (1.0f + __expf(-p4.x)) - p4.x * p4.x;
    d4.y = 1.0f / (1.0f + __expf(-p4.y)) - p4.y * p4.y;
    d4.z = 1.0f / (1.0f + __expf(-p4.z)) - p4.z * p4.z;
    d4.w = 1.0f / (1.0f + __expf(-p4.w)) - p4.w * p4.w;

    for (long long row = (long long)blockIdx.x * rowsPerBlock + rowInBlock;
         row < M;
         row += (long long)gridDim.x * rowsPerBlock)
    {
        const long long idx = row * 32 + lane32;
        const float4 r4 = reinterpret_cast<const float4*>(sr)[idx];
        const float4 i4 = reinterpret_cast<const float4*>(si)[idx];

        // Per-lane partials: dot with p and plain sum, for both real and imag.
        float ar = r4.x * p4.x + r4.y * p4.y + r4.z * p4.z + r4.w * p4.w;
        float sre = r4.x + r4.y + r4.z + r4.w;
        float ai = i4.x * p4.x + i4.y * p4.y + i4.z * p4.z + i4.w * p4.w;
        float sie = i4.x + i4.y + i4.z + i4.w;

        // Butterfly reduce across the 32 lanes of this half-wave.
        // XOR masks <32 never cross the half-wave boundary in a wave64.
        #pragma unroll
        for (int m = 16; m >= 1; m >>= 1) {
            ar  += __shfl_xor(ar,  m, 64);
            sre += __shfl_xor(sre, m, 64);
            ai  += __shfl_xor(ai,  m, 64);
            sie += __shfl_xor(sie, m, 64);
        }

        const float cr = ar + sie;  // coefficient of p_j in out_real
        const float ci = ai - sre;  // coefficient of p_j in out_imag

        float4 o_r, o_i;
        o_r.x = cr * p4.x + r4.x * d4.x - ai;
        o_r.y = cr * p4.y + r4.y * d4.y - ai;
        o_r.z = cr * p4.z + r4.z * d4.z - ai;
        o_r.w = cr * p4.w + r4.w * d4.w - ai;

        o_i.x = ar + ci * p4.x + i4.x * d4.x;
        o_i.y = ar + ci * p4.y + i4.y * d4.y;
        o_i.z = ar + ci * p4.z + i4.z * d4.z;
        o_i.w = ar + ci * p4.w + i4.w * d4.w;

        reinterpret_cast<float4*>(out_r)[idx] = o_r;
        reinterpret_cast<float4*>(out_i)[idx] = o_i;
    }
}

extern "C" void kernel_launch(void* const* d_in, const int* in_sizes, int n_in,
                              void* d_out, int out_size, void* d_ws, size_t ws_size,
                              hipStream_t stream) {
    const float* sr = (const float*)d_in[0];
    const float* si = (const float*)d_in[1];
    const float* p  = (const float*)d_in[2];
    float* out = (float*)d_out;

    const int M = in_sizes[0] / DIM;          // 16*16384 = 262144 rows
    float* out_r = out;
    float* out_i = out + (size_t)M * DIM;

    const int block = 256;
    const int rowsPerBlock = block / 32;      // 8
    int blocks = (M + rowsPerBlock - 1) / rowsPerBlock;  // 32768

    qop_kernel<<<blocks, block, 0, stream>>>(sr, si, p, out_r, out_i, M);
}